// Round 1
// baseline (354.016 us; speedup 1.0000x reference)
//
#include <hip/hip_runtime.h>

#define NEG_INF_F (-4294967295.0f)  // -(2^32)+1, rounds to -2^32 in fp32 like the reference

typedef __attribute__((ext_vector_type(8))) short bf16x8;   // 8 bf16 = 4 VGPRs (MFMA A/B frag)
typedef __attribute__((ext_vector_type(4))) float f32x4;    // MFMA C/D frag

__device__ __forceinline__ unsigned short f2bf(float x) {
    unsigned u = __float_as_uint(x);
    unsigned r = (u + 0x7fffu + ((u >> 16) & 1u)) >> 16;  // RNE
    return (unsigned short)r;
}
__device__ __forceinline__ float bf2f(unsigned short s) {
    return __uint_as_float(((unsigned)s) << 16);
}

// LDS layout. K and h1s use a 16B-granule XOR swizzle (granule g stored at g^row)
// so A-fragment ds_read_b128 (row stride 256B / 128B) avoids 16-way bank conflicts.
struct __align__(16) Smem {
    unsigned short K[200 * 128];     // 51200 B  bf16 keys[b], swizzled
    unsigned short h1s[4][16 * 64];  //  8192 B  per-wave h1 C->A layout scratch, swizzled
    float q[128];                    //   512 B
    float maskf[208];                //   832 B  (only [0,200) initialized)
    float cpart[256];                //  1024 B  4 partial k-chunks of c[n]=q@(W1q+W1d)+b1
    float s[208];                    //   832 B  scores, then softmax weights * (1/200)
    float ppart[128];                //   512 B  weighted-sum partial (t in [100,200))
    float red[16];                   //    64 B  cross-wave reduce scratch
};
static_assert(sizeof(Smem) <= 64 * 1024, "LDS over 64 KiB");

__global__ __launch_bounds__(256, 2)
void attn_fused(const float* __restrict__ Q,    // [2048,128]
                const float* __restrict__ Kg,   // [2048,200,128]
                const int*   __restrict__ kid,  // [2048,200]
                const float* __restrict__ W1,   // [512,64]
                const float* __restrict__ b1,   // [64]
                const float* __restrict__ W2,   // [64,32]
                const float* __restrict__ b2,   // [32]
                const float* __restrict__ W3,   // [32,1]
                const float* __restrict__ b3,   // [1]
                float* __restrict__ out)        // [2048,128]
{
    __shared__ Smem sm;
    const int b    = blockIdx.x;
    const int tid  = threadIdx.x;
    const int wave = tid >> 6;
    const int lane = tid & 63;
    const int l15  = lane & 15;
    const int quad = lane >> 4;

    // ---------------- phase 0: q + mask to LDS ----------------
    if (tid < 128) sm.q[tid] = Q[b * 128 + tid];
    if (tid < 200) sm.maskf[tid] = (kid[b * 200 + tid] != 0) ? 1.0f : 0.0f;
    __syncthreads();

    // ---------------- phase 1a: c[n] partials (wave w does k-chunk w) ----------------
    {
        const int n = tid & 63, kc = tid >> 6;
        float acc = (kc == 0) ? b1[n] : 0.0f;
        #pragma unroll 4
        for (int i = 0; i < 32; ++i) {
            const int k = kc * 32 + i;
            acc += sm.q[k] * (W1[k * 64 + n] + W1[(256 + k) * 64 + n]);
        }
        sm.cpart[kc * 64 + n] = acc;
    }

    // ---------------- phase 1b: stage keys[b] -> LDS bf16 (swizzled) ----------------
    {
        const float4* src = reinterpret_cast<const float4*>(Kg + (size_t)b * 200 * 128);
        #pragma unroll
        for (int r = 0; r < 25; ++r) {
            const int idx4 = tid + 256 * r;        // 6400 float4 total
            const float4 v = src[idx4];
            const int t = idx4 >> 5;               // 32 float4 per row
            const int e = (idx4 & 31) << 2;
            const int g = (e >> 3) ^ (t & 15);     // granule swizzle
            ushort4 pk;
            pk.x = f2bf(v.x); pk.y = f2bf(v.y); pk.z = f2bf(v.z); pk.w = f2bf(v.w);
            *reinterpret_cast<ushort4*>(&sm.K[t * 128 + g * 8 + (e & 7)]) = pk;
        }
    }
    __syncthreads();

    // ---------------- phase 2: per-wave, no sync until scores done ----------------
    // M_b = (W1k - W1d) + diag(q) * W1p, built directly as MFMA B-fragments in regs.
    // B-frag layout: lane(n=l15, k=quad*8+j) [per m89/m120 mappings].
    bf16x8 Mf[4][4];  // [kstep][ntile]
    #pragma unroll
    for (int ks = 0; ks < 4; ++ks) {
        #pragma unroll
        for (int nt = 0; nt < 4; ++nt) {
            const int n = nt * 16 + l15;
            const int kb = ks * 32 + quad * 8;
            bf16x8 f;
            #pragma unroll
            for (int j = 0; j < 8; ++j) {
                const int k = kb + j;
                const float wb = W1[(128 + k) * 64 + n];
                const float wd = W1[(256 + k) * 64 + n];
                const float wp = W1[(384 + k) * 64 + n];
                f[j] = (short)f2bf((wb - wd) + sm.q[k] * wp);
            }
            Mf[ks][nt] = f;
        }
    }
    bf16x8 W2f[2][2];  // [kstep][ntile] of W2 [64,32]
    #pragma unroll
    for (int ks = 0; ks < 2; ++ks) {
        #pragma unroll
        for (int nt = 0; nt < 2; ++nt) {
            const int n = nt * 16 + l15;
            const int kb = ks * 32 + quad * 8;
            bf16x8 f;
            #pragma unroll
            for (int j = 0; j < 8; ++j) f[j] = (short)f2bf(W2[(kb + j) * 32 + n]);
            W2f[ks][nt] = f;
        }
    }
    const float w3a = W3[l15],  w3b = W3[16 + l15];
    const float b2a = b2[l15],  b2b = b2[16 + l15];
    const float b3v = b3[0];
    float cn[4];
    #pragma unroll
    for (int nt = 0; nt < 4; ++nt) {
        const int n = nt * 16 + l15;
        cn[nt] = sm.cpart[n] + sm.cpart[64 + n] + sm.cpart[128 + n] + sm.cpart[192 + n];
    }

    unsigned short* h1w = &sm.h1s[wave][0];
    const f32x4 zero4 = {0.f, 0.f, 0.f, 0.f};

    // wave w owns m-tiles w, w+4, w+8 (w==0 also 12). Tile 12 rows 200..207 read
    // garbage past K[] -- row-contained through both MFMAs, scores forced -inf.
    for (int tile = wave; tile < 13; tile += 4) {
        const int t0 = tile * 16;
        const int t  = t0 + l15;                  // A-frag row for this lane
        f32x4 acc[4] = {zero4, zero4, zero4, zero4};
        #pragma unroll
        for (int ks = 0; ks < 4; ++ks) {
            const int g = (ks * 4 + quad) ^ (t & 15);
            const bf16x8 A = *reinterpret_cast<const bf16x8*>(&sm.K[t * 128 + g * 8]);
            #pragma unroll
            for (int nt = 0; nt < 4; ++nt)
                acc[nt] = __builtin_amdgcn_mfma_f32_16x16x32_bf16(A, Mf[ks][nt], acc[nt], 0, 0, 0);
        }
        // epilogue: + c[n], relu, store bf16 into wave-private scratch in A-layout order
        #pragma unroll
        for (int nt = 0; nt < 4; ++nt) {
            const int n = nt * 16 + l15;
            #pragma unroll
            for (int r = 0; r < 4; ++r) {
                const int m = quad * 4 + r;       // C-layout row
                const float h = fmaxf(acc[nt][r] + cn[nt], 0.0f);
                const int g = (n >> 3) ^ (m & 7);
                h1w[m * 64 + g * 8 + (n & 7)] = f2bf(h);
            }
        }
        // layer 2: [16,64] @ [64,32]
        f32x4 p0 = zero4, p1 = zero4;
        #pragma unroll
        for (int ks = 0; ks < 2; ++ks) {
            const int g = (ks * 4 + quad) ^ (l15 & 7);
            const bf16x8 A2 = *reinterpret_cast<const bf16x8*>(&h1w[l15 * 64 + g * 8]);
            p0 = __builtin_amdgcn_mfma_f32_16x16x32_bf16(A2, W2f[ks][0], p0, 0, 0, 0);
            p1 = __builtin_amdgcn_mfma_f32_16x16x32_bf16(A2, W2f[ks][1], p1, 0, 0, 0);
        }
        // layer 3: relu + dot(W3) in fp32, reduce across the 16 lanes of each quad
        float sv[4];
        #pragma unroll
        for (int r = 0; r < 4; ++r)
            sv[r] = fmaxf(p0[r] + b2a, 0.f) * w3a + fmaxf(p1[r] + b2b, 0.f) * w3b;
        #pragma unroll
        for (int off = 1; off < 16; off <<= 1) {
            #pragma unroll
            for (int r = 0; r < 4; ++r) sv[r] += __shfl_xor(sv[r], off);
        }
        if (l15 == 0) {
            #pragma unroll
            for (int r = 0; r < 4; ++r) {
                const int tt = t0 + quad * 4 + r;
                if (tt < 200)
                    sm.s[tt] = (sm.maskf[tt] != 0.0f) ? (sv[r] + b3v) : NEG_INF_F;
                else if (tt < 208)
                    sm.s[tt] = -__builtin_inff();
            }
        }
    }
    __syncthreads();

    // ---------------- phase 3: masked softmax over t, fold in 1/200 ----------------
    {
        const float v = (tid < 208) ? sm.s[tid] : -__builtin_inff();
        float m = v;
        #pragma unroll
        for (int off = 32; off >= 1; off >>= 1) m = fmaxf(m, __shfl_xor(m, off));
        if (lane == 0) sm.red[wave] = m;
        __syncthreads();
        m = fmaxf(fmaxf(sm.red[0], sm.red[1]), fmaxf(sm.red[2], sm.red[3]));
        const float ev = (tid < 208) ? __expf(v - m) : 0.0f;
        float ssum = ev;
        #pragma unroll
        for (int off = 32; off >= 1; off >>= 1) ssum += __shfl_xor(ssum, off);
        if (lane == 0) sm.red[8 + wave] = ssum;
        __syncthreads();
        const float S = sm.red[8] + sm.red[9] + sm.red[10] + sm.red[11];
        const float inv = 1.0f / (S * 200.0f);   // softmax normalize + mean(/T)
        if (tid < 208) sm.s[tid] = ev * inv;
    }
    __syncthreads();

    // ---------------- phase 4: out[e] = sum_t w[t] * K[t][e] ----------------
    {
        const int e = tid & 127;
        const int h = tid >> 7;                  // t-halves
        float acc2 = 0.0f;
        const int tbeg = h * 100;
        for (int tt = tbeg; tt < tbeg + 100; ++tt) {
            const float wv = sm.s[tt];           // broadcast across lanes
            const int g = (e >> 3) ^ (tt & 15);
            acc2 += wv * bf2f(sm.K[tt * 128 + g * 8 + (e & 7)]);
        }
        if (h == 1) sm.ppart[e] = acc2;
        __syncthreads();
        if (h == 0) out[(size_t)b * 128 + e] = acc2 + sm.ppart[e];
    }
}

extern "C" void kernel_launch(void* const* d_in, const int* in_sizes, int n_in,
                              void* d_out, int out_size, void* d_ws, size_t ws_size,
                              hipStream_t stream) {
    (void)in_sizes; (void)n_in; (void)out_size; (void)d_ws; (void)ws_size;
    attn_fused<<<dim3(2048), dim3(256), 0, stream>>>(
        (const float*)d_in[0], (const float*)d_in[1], (const int*)d_in[2],
        (const float*)d_in[3], (const float*)d_in[4], (const float*)d_in[5],
        (const float*)d_in[6], (const float*)d_in[7], (const float*)d_in[8],
        (float*)d_out);
}

// Round 2
// 345.811 us; speedup vs baseline: 1.0237x; 1.0237x over previous
//
#include <hip/hip_runtime.h>
#include <hip/hip_bf16.h>

#define NEG_INF_F (-4294967295.0f)  // -(2^32)+1, matches reference padding

typedef __attribute__((ext_vector_type(8))) short bf16x8;   // MFMA A/B frag (4 VGPRs)
typedef __attribute__((ext_vector_type(4))) float f32x4;    // MFMA C/D frag

__device__ __forceinline__ unsigned short f2bf(float x) {
    unsigned u = __float_as_uint(x);
    return (unsigned short)((u + 0x7fffu + ((u >> 16) & 1u)) >> 16);  // RNE
}
__device__ __forceinline__ unsigned f2bf2(float a, float b) {
    // packed pair -> v_cvt_pk_bf16_f32 on gfx950
    __hip_bfloat162 h2 = __float22bfloat162_rn(make_float2(a, b));
    unsigned r; __builtin_memcpy(&r, &h2, 4); return r;
}
__device__ __forceinline__ float bf2f(unsigned short s) {
    return __uint_as_float(((unsigned)s) << 16);
}

// LDS layout. K uses a 16B-granule XOR swizzle (granule g stored at g^(t&15)) so
// A-fragment ds_read_b128 avoids bank conflicts. h1s doubles as the cooperative
// M-build staging buffer (two 64x64 halves, granule-swizzled by n&7).
struct __align__(16) Smem {
    unsigned short K[200 * 128];     // 51200 B  bf16 keys[b], swizzled
    unsigned short h1s[4][16 * 64];  //  8192 B  M-build halves / per-wave h1 scratch
    float q[128];                    //   512 B
    float maskf[208];                //   832 B
    float cpart[256];                //  1024 B  partials of c[n] = q@(W1q+W1d)+b1
    float s[208];                    //   832 B  scores -> softmax weights * (1/200)
    float ppart[128];                //   512 B
    float red[16];                   //    64 B
};
static_assert(sizeof(Smem) <= 64 * 1024, "LDS over 64 KiB");

__global__ __launch_bounds__(256, 2)
void attn_fused(const float* __restrict__ Q,    // [2048,128]
                const float* __restrict__ Kg,   // [2048,200,128]
                const int*   __restrict__ kid,  // [2048,200]
                const float* __restrict__ W1,   // [512,64]
                const float* __restrict__ b1,   // [64]
                const float* __restrict__ W2,   // [64,32]
                const float* __restrict__ b2,   // [32]
                const float* __restrict__ W3,   // [32,1]
                const float* __restrict__ b3,   // [1]
                float* __restrict__ out)        // [2048,128]
{
    __shared__ Smem sm;
    const int b    = blockIdx.x;
    const int tid  = threadIdx.x;
    const int wave = tid >> 6;
    const int lane = tid & 63;
    const int l15  = lane & 15;
    const int quad = lane >> 4;

    // ---------------- phase 0+1b: stage keys[b] -> LDS bf16 (swizzled); q+mask ----
    {
        const float4* src = reinterpret_cast<const float4*>(Kg + (size_t)b * 200 * 128);
        #pragma unroll
        for (int r = 0; r < 25; ++r) {
            const int idx4 = tid + 256 * r;        // 6400 float4 total
            const float4 v = src[idx4];
            const int t = idx4 >> 5;               // 32 float4 per row
            const int e = (idx4 & 31) << 2;
            const int g = (e >> 3) ^ (t & 15);     // granule swizzle
            uint2 pk;
            pk.x = f2bf2(v.x, v.y);
            pk.y = f2bf2(v.z, v.w);
            *reinterpret_cast<uint2*>(&sm.K[t * 128 + g * 8 + (e & 7)]) = pk;
        }
    }
    if (tid < 128) sm.q[tid] = Q[b * 128 + tid];
    if (tid < 200) sm.maskf[tid] = (kid[b * 200 + tid] != 0) ? 1.0f : 0.0f;
    __syncthreads();

    // ---------------- small weights into regs (overlaps M build) ----------------
    bf16x8 W2f[2][2];  // B-frags of W2 [64,32]: lane(n=l15, k=quad*8+j)
    #pragma unroll
    for (int ks = 0; ks < 2; ++ks) {
        #pragma unroll
        for (int nt = 0; nt < 2; ++nt) {
            const int n = nt * 16 + l15;
            const int kb = ks * 32 + quad * 8;
            bf16x8 f;
            #pragma unroll
            for (int j = 0; j < 8; ++j) f[j] = (short)f2bf(W2[(kb + j) * 32 + n]);
            W2f[ks][nt] = f;
        }
    }
    const float w3a = W3[l15],  w3b = W3[16 + l15];
    const float b2a = b2[l15],  b2b = b2[16 + l15];
    const float b3v = b3[0];

    // ---------------- phase 1a: c[n] partials (wave w does k-chunk w) -----------
    {
        const int n = tid & 63, kc = tid >> 6;
        float acc = (kc == 0) ? b1[n] : 0.0f;
        #pragma unroll 4
        for (int i = 0; i < 32; ++i) {
            const int k = kc * 32 + i;
            acc += sm.q[k] * (W1[k * 64 + n] + W1[(256 + k) * 64 + n]);
        }
        sm.cpart[kc * 64 + n] = acc;
    }

    // ---------------- phase 1c: cooperative M build, two 64-k halves ------------
    // M_b[k][n] = (W1k - W1d)[k][n] + q[k]*W1p[k][n], stored transposed Mt[n][k']
    // (bf16, 16B-granule swizzle g^(n&7)) in the h1s buffer, then read out as
    // B-fragments: lane(n=l15, k=quad*8+j).
    bf16x8 Mf[4][4];  // [kstep][ntile]
    {
        unsigned short* Mbuf = &sm.h1s[0][0];
        const int n   = tid & 63;
        const int w16 = (tid >> 6) * 16;
        #pragma unroll
        for (int hf = 0; hf < 2; ++hf) {
            #pragma unroll
            for (int j = 0; j < 16; j += 2) {
                const int kp = w16 + j;            // k' in [0,64)
                const int k  = hf * 64 + kp;
                const float v0 = (W1[(128 + k) * 64 + n] - W1[(256 + k) * 64 + n])
                               + sm.q[k] * W1[(384 + k) * 64 + n];
                const float v1 = (W1[(129 + k) * 64 + n] - W1[(257 + k) * 64 + n])
                               + sm.q[k + 1] * W1[(385 + k) * 64 + n];
                const int g = (kp >> 3) ^ (n & 7);
                *reinterpret_cast<unsigned*>(&Mbuf[n * 64 + g * 8 + (kp & 7)]) = f2bf2(v0, v1);
            }
            __syncthreads();
            #pragma unroll
            for (int ksl = 0; ksl < 2; ++ksl) {
                #pragma unroll
                for (int nt = 0; nt < 4; ++nt) {
                    const int nn = nt * 16 + l15;
                    const int g  = (ksl * 4 + quad) ^ (nn & 7);
                    Mf[hf * 2 + ksl][nt] = *reinterpret_cast<const bf16x8*>(&Mbuf[nn * 64 + g * 8]);
                }
            }
            __syncthreads();
        }
    }
    float cn[4];
    #pragma unroll
    for (int nt = 0; nt < 4; ++nt) {
        const int n = nt * 16 + l15;
        cn[nt] = sm.cpart[n] + sm.cpart[64 + n] + sm.cpart[128 + n] + sm.cpart[192 + n];
    }

    unsigned short* h1w = &sm.h1s[wave][0];
    const f32x4 zero4 = {0.f, 0.f, 0.f, 0.f};

    // ---------------- phase 2: tile loop, waves independent ----------------
    // wave w owns m-tiles w, w+4, w+8 (w==0 also 12). Tile 12 rows 200..207 read
    // garbage past K[] -- row-contained through both MFMAs, scores forced -inf.
    for (int tile = wave; tile < 13; tile += 4) {
        const int t0 = tile * 16;
        const int t  = t0 + l15;                  // A-frag row for this lane
        f32x4 acc[4] = {zero4, zero4, zero4, zero4};
        #pragma unroll
        for (int ks = 0; ks < 4; ++ks) {
            const int g = (ks * 4 + quad) ^ (t & 15);
            const bf16x8 A = *reinterpret_cast<const bf16x8*>(&sm.K[t * 128 + g * 8]);
            #pragma unroll
            for (int nt = 0; nt < 4; ++nt)
                acc[nt] = __builtin_amdgcn_mfma_f32_16x16x32_bf16(A, Mf[ks][nt], acc[nt], 0, 0, 0);
        }
        // epilogue: + c[n], relu, bf16 -> wave-private scratch in A-layout order
        #pragma unroll
        for (int nt = 0; nt < 4; ++nt) {
            const int n = nt * 16 + l15;
            #pragma unroll
            for (int r = 0; r < 4; ++r) {
                const int m = quad * 4 + r;       // C-layout row
                const float h = fmaxf(acc[nt][r] + cn[nt], 0.0f);
                const int g = (n >> 3) ^ (m & 7);
                h1w[m * 64 + g * 8 + (n & 7)] = f2bf(h);
            }
        }
        // layer 2: [16,64] @ [64,32]
        f32x4 p0 = zero4, p1 = zero4;
        #pragma unroll
        for (int ks = 0; ks < 2; ++ks) {
            const int g = (ks * 4 + quad) ^ (l15 & 7);
            const bf16x8 A2 = *reinterpret_cast<const bf16x8*>(&h1w[l15 * 64 + g * 8]);
            p0 = __builtin_amdgcn_mfma_f32_16x16x32_bf16(A2, W2f[ks][0], p0, 0, 0, 0);
            p1 = __builtin_amdgcn_mfma_f32_16x16x32_bf16(A2, W2f[ks][1], p1, 0, 0, 0);
        }
        // layer 3: relu + dot(W3) in fp32, reduce across the 16 lanes of each quad
        float sv[4];
        #pragma unroll
        for (int r = 0; r < 4; ++r)
            sv[r] = fmaxf(p0[r] + b2a, 0.f) * w3a + fmaxf(p1[r] + b2b, 0.f) * w3b;
        #pragma unroll
        for (int off = 1; off < 16; off <<= 1) {
            #pragma unroll
            for (int r = 0; r < 4; ++r) sv[r] += __shfl_xor(sv[r], off);
        }
        if (l15 == 0) {
            #pragma unroll
            for (int r = 0; r < 4; ++r) {
                const int tt = t0 + quad * 4 + r;
                if (tt < 200)
                    sm.s[tt] = (sm.maskf[tt] != 0.0f) ? (sv[r] + b3v) : NEG_INF_F;
                else if (tt < 208)
                    sm.s[tt] = -__builtin_inff();
            }
        }
    }
    __syncthreads();

    // ---------------- phase 3: masked softmax over t, fold in 1/200 ----------------
    {
        const float v = (tid < 208) ? sm.s[tid] : -__builtin_inff();
        float m = v;
        #pragma unroll
        for (int off = 32; off >= 1; off >>= 1) m = fmaxf(m, __shfl_xor(m, off));
        if (lane == 0) sm.red[wave] = m;
        __syncthreads();
        m = fmaxf(fmaxf(sm.red[0], sm.red[1]), fmaxf(sm.red[2], sm.red[3]));
        const float ev = (tid < 208) ? __expf(v - m) : 0.0f;
        float ssum = ev;
        #pragma unroll
        for (int off = 32; off >= 1; off >>= 1) ssum += __shfl_xor(ssum, off);
        if (lane == 0) sm.red[8 + wave] = ssum;
        __syncthreads();
        const float S = sm.red[8] + sm.red[9] + sm.red[10] + sm.red[11];
        const float inv = 1.0f / (S * 200.0f);   // softmax normalize + mean(/T)
        if (tid < 208) sm.s[tid] = ev * inv;
    }
    __syncthreads();

    // ---------------- phase 4: out[e] = sum_t w[t] * K[t][e], 4-way ILP ---------
    {
        const int e  = tid & 127;
        const int h  = tid >> 7;                 // t-halves
        const int e3 = e & 7;
        const int eh = e >> 3;
        float a0 = 0.f, a1 = 0.f, a2 = 0.f, a3 = 0.f;
        const int tb0 = h * 100;
        #pragma unroll
        for (int i = 0; i < 25; ++i) {
            const int tb = tb0 + i * 4;
            const float4 wv = *reinterpret_cast<const float4*>(&sm.s[tb]);
            a0 += wv.x * bf2f(sm.K[(tb + 0) * 128 + ((eh ^ ((tb + 0) & 15)) * 8) + e3]);
            a1 += wv.y * bf2f(sm.K[(tb + 1) * 128 + ((eh ^ ((tb + 1) & 15)) * 8) + e3]);
            a2 += wv.z * bf2f(sm.K[(tb + 2) * 128 + ((eh ^ ((tb + 2) & 15)) * 8) + e3]);
            a3 += wv.w * bf2f(sm.K[(tb + 3) * 128 + ((eh ^ ((tb + 3) & 15)) * 8) + e3]);
        }
        const float acc2 = (a0 + a1) + (a2 + a3);
        if (h == 1) sm.ppart[e] = acc2;
        __syncthreads();
        if (h == 0) out[(size_t)b * 128 + e] = acc2 + sm.ppart[e];
    }
}

extern "C" void kernel_launch(void* const* d_in, const int* in_sizes, int n_in,
                              void* d_out, int out_size, void* d_ws, size_t ws_size,
                              hipStream_t stream) {
    (void)in_sizes; (void)n_in; (void)out_size; (void)d_ws; (void)ws_size;
    attn_fused<<<dim3(2048), dim3(256), 0, stream>>>(
        (const float*)d_in[0], (const float*)d_in[1], (const int*)d_in[2],
        (const float*)d_in[3], (const float*)d_in[4], (const float*)d_in[5],
        (const float*)d_in[6], (const float*)d_in[7], (const float*)d_in[8],
        (float*)d_out);
}